// Round 1
// baseline (453.385 us; speedup 1.0000x reference)
//
#include <hip/hip_runtime.h>

#define B_ 8
#define H_ 128
#define W_ 256
#define C_ 128
#define D_ 128

typedef __attribute__((ext_vector_type(4))) float f32x4;
typedef __attribute__((ext_vector_type(8))) short s16x8;

__device__ __forceinline__ unsigned short f2bf(float f) {
    union { float f; unsigned u; } v; v.f = f;
    unsigned r = v.u + 0x7fffu + ((v.u >> 16) & 1u);   // RNE
    return (unsigned short)(r >> 16);
}
__device__ __forceinline__ float relu(float v) { return fmaxf(v, 0.f); }

// ---------------------------------------------------------------- K0
// c1x[b,i,w] = b1 + sum_{k,c} x[b,i,w+k-4,c]*w1[k,c]  (raw, pre-relu)
// s1[k] = sum_c w1[k,c];  w2t[d][c] = bf16(w2[0,4,c,d])
__global__ __launch_bounds__(256, 4) void k0_conv1(
    const float* __restrict__ x, const float* __restrict__ w1,
    const float* __restrict__ b1, const float* __restrict__ w2,
    float* __restrict__ c1x, float* __restrict__ s1,
    unsigned short* __restrict__ w2t) {
    int bid = blockIdx.x, tid = threadIdx.x;
    if (bid >= B_ * H_) {                      // w2t staging blocks
        int idx = (bid - B_ * H_) * 256 + tid; // 0..16383
        int d = idx & (D_ - 1), c = idx >> 7;
        w2t[d * C_ + c] = f2bf(w2[4 * C_ * D_ + c * D_ + d]);
        return;
    }
    if (bid == 0 && tid < 9) {
        float s = 0.f;
        for (int c = 0; c < C_; ++c) s += w1[tid * C_ + c];
        s1[tid] = s;
    }
    __shared__ float w1s[9 * C_];
    for (int t = tid; t < 9 * C_; t += 256) w1s[t] = w1[t];
    __syncthreads();

    int wv = tid >> 6, l = tid & 63;
    const float* xr = x + (size_t)bid * (W_ * C_);
    float w1a[9], w1b[9];
#pragma unroll
    for (int k = 0; k < 9; ++k) { w1a[k] = w1s[k * C_ + l]; w1b[k] = w1s[k * C_ + l + 64]; }
    float b1v = b1[0];

    for (int ch = 0; ch < 8; ++ch) {
        int p0 = wv * 64 + ch * 8;
        float part[8] = {0.f,0.f,0.f,0.f,0.f,0.f,0.f,0.f};
#pragma unroll
        for (int wr = 0; wr < 16; ++wr) {
            int wk = p0 + wr - 4;
            float v0 = 0.f, v1 = 0.f;
            if (wk >= 0 && wk < W_) { v0 = xr[wk * C_ + l]; v1 = xr[wk * C_ + l + 64]; }
#pragma unroll
            for (int pi = 0; pi < 8; ++pi) {
                int k = wr - pi;
                if (k >= 0 && k < 9) part[pi] += v0 * w1a[k] + v1 * w1b[k];
            }
        }
#pragma unroll
        for (int pi = 0; pi < 8; ++pi) {
            float v = part[pi];
#pragma unroll
            for (int off = 32; off > 0; off >>= 1) v += __shfl_down(v, off, 64);
            if (l == 0) c1x[(size_t)bid * W_ + p0 + pi] = v + b1v;
        }
    }
}

// ---------------------------------------------------------------- K1
// z row = x[rowY] + sc[w];  v = relu(z@W2+b2);  p[0]=z[0]; p[w+1]=z[w+1]+v[w]
__global__ __launch_bounds__(256, 2) void k1_rows_gemm(
    const float* __restrict__ x, const float* __restrict__ b2,
    const float* __restrict__ c1x_all, const float* __restrict__ s1,
    const unsigned short* __restrict__ w2t, float* __restrict__ p_out) {
    int bid = blockIdx.x;            // row index b*H + i
    int b = bid >> 7, i = bid & 127;
    int tid = threadIdx.x;
    __shared__ float sc[W_];
    const float* c1 = c1x_all + (size_t)b * H_ * W_;

    int rowY;
    if (i == H_ - 1) rowY = H_ - 1;
    else if (i <= H_ - 3) rowY = (i - 1) & (H_ - 1);
    else rowY = H_ - 2;
    {   // phase 0: per-w scalar
        int w = tid;
        float scv;
        if (i == H_ - 1) {
            scv = relu(c1[(H_ - 2) * W_ + w]);        // z = y[H-1] = x[H-1] + t[H-2]
        } else {
            int iu = (i <= H_ - 3) ? i : (H_ - 1);
            float cu = c1[iu * W_ + w];
            if (iu >= 1) {
                const float* tp = c1 + (iu - 1) * W_;
#pragma unroll
                for (int k = 0; k < 9; ++k) {
                    int wk = w + k - 4;
                    if (wk >= 0 && wk < W_) cu += relu(tp[wk]) * s1[k];
                }
            }
            float tY = (rowY >= 1) ? relu(c1[(rowY - 1) * W_ + w]) : 0.f;
            scv = tY + relu(cu);
        }
        sc[w] = scv;
    }
    __syncthreads();

    const float* zrow = x + ((size_t)b * H_ + rowY) * (W_ * C_);
    float* prow = p_out + (size_t)bid * (W_ * C_);
    if (tid < C_) prow[tid] = zrow[tid] + sc[0];      // p[0] = z[0]

    int wv = tid >> 6, l = tid & 63, q = l >> 4, l15 = l & 15;
    int m0 = wv * 64;
    f32x4 acc[4][8];
#pragma unroll
    for (int mt = 0; mt < 4; ++mt)
#pragma unroll
        for (int nt = 0; nt < 8; ++nt) acc[mt][nt] = (f32x4){0.f, 0.f, 0.f, 0.f};

#pragma unroll
    for (int k0 = 0; k0 < C_; k0 += 32) {
        s16x8 af[4], bfr[8];
#pragma unroll
        for (int mt = 0; mt < 4; ++mt) {
            int w = m0 + mt * 16 + l15;
            const float* ap = zrow + w * C_ + k0 + q * 8;
            float s = sc[w];
            f32x4 f0 = *(const f32x4*)ap;
            f32x4 f1 = *(const f32x4*)(ap + 4);
            s16x8 t;
#pragma unroll
            for (int j = 0; j < 4; ++j) t[j] = (short)f2bf(f0[j] + s);
#pragma unroll
            for (int j = 0; j < 4; ++j) t[4 + j] = (short)f2bf(f1[j] + s);
            af[mt] = t;
        }
#pragma unroll
        for (int nt = 0; nt < 8; ++nt)
            bfr[nt] = *(const s16x8*)(w2t + (nt * 16 + l15) * C_ + k0 + q * 8);
#pragma unroll
        for (int mt = 0; mt < 4; ++mt)
#pragma unroll
            for (int nt = 0; nt < 8; ++nt)
                acc[mt][nt] = __builtin_amdgcn_mfma_f32_16x16x32_bf16(af[mt], bfr[nt], acc[mt][nt], 0, 0, 0);
    }
    // epilogue: p[w+1] = z[w+1] + sc[w+1] + relu(acc + b2)
#pragma unroll
    for (int nt = 0; nt < 8; ++nt) {
        int c = nt * 16 + l15;
        float bias = b2[c];
#pragma unroll
        for (int mt = 0; mt < 4; ++mt) {
#pragma unroll
            for (int r = 0; r < 4; ++r) {
                int w = m0 + mt * 16 + q * 4 + r;
                if (w < W_ - 1) {
                    float v = relu(acc[mt][nt][r] + bias);
                    prow[(w + 1) * C_ + c] = zrow[(w + 1) * C_ + c] + sc[w + 1] + v;
                }
            }
        }
    }
}

// ---------------------------------------------------------------- K2
// r = relu(p@W2+b2); q[w]=r[w]+p[(w-1)%W] (w<=W-3); q[W-2]=r[W-1]+p[W-2];
// q[W-1]=p[W-1] (no-op in place). In-place: reads before barrier, stores after.
__global__ __launch_bounds__(256, 2) void k2_pass34(
    const float* __restrict__ b2, const unsigned short* __restrict__ w2t,
    float* __restrict__ pq) {
    int bid = blockIdx.x;
    int tid = threadIdx.x;
    float* prow = pq + (size_t)bid * (W_ * C_);
    int wv = tid >> 6, l = tid & 63, q = l >> 4, l15 = l & 15;
    int m0 = wv * 64;
    f32x4 acc[4][8];
#pragma unroll
    for (int mt = 0; mt < 4; ++mt)
#pragma unroll
        for (int nt = 0; nt < 8; ++nt) acc[mt][nt] = (f32x4){0.f, 0.f, 0.f, 0.f};

#pragma unroll
    for (int k0 = 0; k0 < C_; k0 += 32) {
        s16x8 af[4], bfr[8];
#pragma unroll
        for (int mt = 0; mt < 4; ++mt) {
            int w = m0 + mt * 16 + l15;
            const float* ap = prow + w * C_ + k0 + q * 8;
            f32x4 f0 = *(const f32x4*)ap;
            f32x4 f1 = *(const f32x4*)(ap + 4);
            s16x8 t;
#pragma unroll
            for (int j = 0; j < 4; ++j) t[j] = (short)f2bf(f0[j]);
#pragma unroll
            for (int j = 0; j < 4; ++j) t[4 + j] = (short)f2bf(f1[j]);
            af[mt] = t;
        }
#pragma unroll
        for (int nt = 0; nt < 8; ++nt)
            bfr[nt] = *(const s16x8*)(w2t + (nt * 16 + l15) * C_ + k0 + q * 8);
#pragma unroll
        for (int mt = 0; mt < 4; ++mt)
#pragma unroll
            for (int nt = 0; nt < 8; ++nt)
                acc[mt][nt] = __builtin_amdgcn_mfma_f32_16x16x32_bf16(af[mt], bfr[nt], acc[mt][nt], 0, 0, 0);
    }
    // epilogue: compute q into registers (reads of p all happen here)
#pragma unroll
    for (int nt = 0; nt < 8; ++nt) {
        int c = nt * 16 + l15;
        float bias = b2[c];
#pragma unroll
        for (int mt = 0; mt < 4; ++mt) {
#pragma unroll
            for (int r = 0; r < 4; ++r) {
                int w = m0 + mt * 16 + q * 4 + r;
                float rr = relu(acc[mt][nt][r] + bias);
                float qv = 0.f;
                if (w <= W_ - 3) qv = rr + prow[((w - 1) & (W_ - 1)) * C_ + c];
                else if (w == W_ - 1) qv = rr + prow[(W_ - 2) * C_ + c];
                acc[mt][nt][r] = qv;
            }
        }
    }
    __syncthreads();   // all p reads retired above; now safe to overwrite
#pragma unroll
    for (int nt = 0; nt < 8; ++nt) {
        int c = nt * 16 + l15;
#pragma unroll
        for (int mt = 0; mt < 4; ++mt) {
#pragma unroll
            for (int r = 0; r < 4; ++r) {
                int w = m0 + mt * 16 + q * 4 + r;
                if (w <= W_ - 3) prow[w * C_ + c] = acc[mt][nt][r];
                else if (w == W_ - 1) prow[(W_ - 2) * C_ + c] = acc[mt][nt][r];
                // w == W_-2: r unused; q[W-1] = p[W-1] stays in place
            }
        }
    }
}

extern "C" void kernel_launch(void* const* d_in, const int* in_sizes, int n_in,
                              void* d_out, int out_size, void* d_ws, size_t ws_size,
                              hipStream_t stream) {
    const float* x  = (const float*)d_in[0];
    const float* w1 = (const float*)d_in[1];
    const float* b1 = (const float*)d_in[2];
    const float* w2 = (const float*)d_in[3];
    const float* b2 = (const float*)d_in[4];
    float* out = (float*)d_out;

    float* wsf = (float*)d_ws;
    float* c1x = wsf;                                  // B*H*W = 262144 floats
    float* s1  = wsf + (size_t)B_ * H_ * W_;           // 9 floats
    unsigned short* w2t = (unsigned short*)(wsf + (size_t)B_ * H_ * W_ + 16); // 16B-aligned, 32 KiB

    k0_conv1<<<B_ * H_ + (C_ * D_) / 256, 256, 0, stream>>>(x, w1, b1, w2, c1x, s1, w2t);
    k1_rows_gemm<<<B_ * H_, 256, 0, stream>>>(x, b2, c1x, s1, w2t, out);
    k2_pass34<<<B_ * H_, 256, 0, stream>>>(b2, w2t, out);
}

// Round 2
// 404.887 us; speedup vs baseline: 1.1198x; 1.1198x over previous
//
#include <hip/hip_runtime.h>

#define B_ 8
#define H_ 128
#define W_ 256
#define C_ 128
#define D_ 128
#define PS 136   // p_lds row stride in shorts (272 B -> bank offset +4/row, 2-way max = free)

typedef __attribute__((ext_vector_type(4))) float f32x4;
typedef __attribute__((ext_vector_type(8))) short s16x8;
typedef __attribute__((ext_vector_type(4))) unsigned short u16x4;

__device__ __forceinline__ unsigned short f2bf(float f) {
    union { float f; unsigned u; } v; v.f = f;
    unsigned r = v.u + 0x7fffu + ((v.u >> 16) & 1u);   // RNE
    return (unsigned short)(r >> 16);
}
__device__ __forceinline__ float bf2f(unsigned short u) {
    union { unsigned u; float f; } v; v.u = ((unsigned)u) << 16; return v.f;
}
__device__ __forceinline__ float relu(float v) { return fmaxf(v, 0.f); }

// ---------------------------------------------------------------- K0
// c1x[b,i,w] = b1 + sum_{k,c} x[b,i,w+k-4,c]*w1[k,c]  (raw, pre-relu)
// s1[k] = sum_c w1[k,c];  w2t[d][c] = bf16(w2[0,4,c,d]); cs2[d] = sum_c w2[0,4,c,d]
// xb = bf16(x) (if enabled)
__global__ __launch_bounds__(256, 4) void k0_conv1(
    const float* __restrict__ x, const float* __restrict__ w1,
    const float* __restrict__ b1, const float* __restrict__ w2,
    float* __restrict__ c1x, float* __restrict__ s1,
    unsigned short* __restrict__ w2t, float* __restrict__ cs2,
    unsigned short* __restrict__ xb_out) {
    int bid = blockIdx.x, tid = threadIdx.x;
    if (bid >= B_ * H_) {                      // w2t staging blocks
        int idx = (bid - B_ * H_) * 256 + tid; // 0..16383
        int d = idx & (D_ - 1), c = idx >> 7;
        w2t[d * C_ + c] = f2bf(w2[4 * C_ * D_ + c * D_ + d]);
        if (bid == B_ * H_ && tid < D_) {      // cs2 column sums (fp32)
            float s = 0.f;
            for (int cc = 0; cc < C_; ++cc) s += w2[4 * C_ * D_ + cc * D_ + tid];
            cs2[tid] = s;
        }
        return;
    }
    if (bid == 0 && tid < 9) {
        float s = 0.f;
        for (int c = 0; c < C_; ++c) s += w1[tid * C_ + c];
        s1[tid] = s;
    }
    __shared__ float w1s[9 * C_];
    for (int t = tid; t < 9 * C_; t += 256) w1s[t] = w1[t];

    const float* xr = x + (size_t)bid * (W_ * C_);
    if (xb_out) {                              // bf16 copy of x (row-local, L2-hot)
        const f32x4* xr4 = (const f32x4*)xr;
        u16x4* xb4 = (u16x4*)(xb_out + (size_t)bid * (W_ * C_));
        for (int t = tid; t < (W_ * C_) / 4; t += 256) {
            f32x4 v = xr4[t];
            u16x4 o;
#pragma unroll
            for (int j = 0; j < 4; ++j) o[j] = f2bf(v[j]);
            xb4[t] = o;
        }
    }
    __syncthreads();

    int wv = tid >> 6, l = tid & 63;
    float w1a[9], w1b[9];
#pragma unroll
    for (int k = 0; k < 9; ++k) { w1a[k] = w1s[k * C_ + l]; w1b[k] = w1s[k * C_ + l + 64]; }
    float b1v = b1[0];

    for (int ch = 0; ch < 8; ++ch) {
        int p0 = wv * 64 + ch * 8;
        float part[8] = {0.f,0.f,0.f,0.f,0.f,0.f,0.f,0.f};
#pragma unroll
        for (int wr = 0; wr < 16; ++wr) {
            int wk = p0 + wr - 4;
            float v0 = 0.f, v1 = 0.f;
            if (wk >= 0 && wk < W_) { v0 = xr[wk * C_ + l]; v1 = xr[wk * C_ + l + 64]; }
#pragma unroll
            for (int pi = 0; pi < 8; ++pi) {
                int k = wr - pi;
                if (k >= 0 && k < 9) part[pi] += v0 * w1a[k] + v1 * w1b[k];
            }
        }
#pragma unroll
        for (int pi = 0; pi < 8; ++pi) {
            float v = part[pi];
#pragma unroll
            for (int off = 32; off > 0; off >>= 1) v += __shfl_down(v, off, 64);
            if (l == 0) c1x[(size_t)bid * W_ + p0 + pi] = v + b1v;
        }
    }
}

// ---------------------------------------------------------------- K12 (fused K1+K2)
// sc[w] built from c1x; GEMM1: v = relu(x@W2 + sc*cs2 + b2)  [rank-1 sc fold]
// p[w+1] = x[w+1] + sc[w+1] + v[w] -> bf16 in LDS (q[W-1]=p[W-1] stored exact fp32)
// GEMM2 on LDS p; q[w] = r[w] + p[(w-1)&255] (w<=W-3); q[W-2] = r[W-1] + p[W-2]
__global__ __launch_bounds__(256, 2) void k12_fused(
    const float* __restrict__ x, const unsigned short* __restrict__ xb,
    const float* __restrict__ b2, const float* __restrict__ c1x_all,
    const float* __restrict__ s1, const unsigned short* __restrict__ w2t,
    const float* __restrict__ cs2, float* __restrict__ qout) {
    __shared__ unsigned short p_lds[W_ * PS];   // 69632 B
    __shared__ float sc[W_];                    // 1024 B
    int bid = blockIdx.x;            // row index b*H + i
    int b = bid >> 7, i = bid & 127;
    int tid = threadIdx.x;
    const float* c1 = c1x_all + (size_t)b * H_ * W_;

    int rowY;
    if (i == H_ - 1) rowY = H_ - 1;
    else if (i <= H_ - 3) rowY = (i - 1) & (H_ - 1);
    else rowY = H_ - 2;
    {   // phase 0: per-w scalar (verified in round 1)
        int w = tid;
        float scv;
        if (i == H_ - 1) {
            scv = relu(c1[(H_ - 2) * W_ + w]);
        } else {
            int iu = (i <= H_ - 3) ? i : (H_ - 1);
            float cu = c1[iu * W_ + w];
            if (iu >= 1) {
                const float* tp = c1 + (iu - 1) * W_;
#pragma unroll
                for (int k = 0; k < 9; ++k) {
                    int wk = w + k - 4;
                    if (wk >= 0 && wk < W_) cu += relu(tp[wk]) * s1[k];
                }
            }
            float tY = (rowY >= 1) ? relu(c1[(rowY - 1) * W_ + w]) : 0.f;
            scv = tY + relu(cu);
        }
        sc[w] = scv;
    }
    __syncthreads();

    const float* zrow = x + ((size_t)b * H_ + rowY) * (W_ * C_);
    const unsigned short* zb = xb ? xb + ((size_t)b * H_ + rowY) * (W_ * C_) : (const unsigned short*)0;
    float* qrow = qout + (size_t)bid * (W_ * C_);

    if (tid < C_) {                  // p[0] = z[0] = x[0] + sc[0]
        float z0 = (zb ? bf2f(zb[tid]) : zrow[tid]) + sc[0];
        p_lds[tid] = f2bf(z0);
    }

    int wv = tid >> 6, l = tid & 63, q = l >> 4, l15 = l & 15;
    int m0 = wv * 64;
    float b2v[8], cs2v[8];
#pragma unroll
    for (int nt = 0; nt < 8; ++nt) { int c = nt * 16 + l15; b2v[nt] = b2[c]; cs2v[nt] = cs2[c]; }

    f32x4 acc[4][8];
#pragma unroll
    for (int mt = 0; mt < 4; ++mt)
#pragma unroll
        for (int nt = 0; nt < 8; ++nt) acc[mt][nt] = (f32x4){0.f, 0.f, 0.f, 0.f};

    // ---- GEMM1: A = bf16(x row) (sc folded as rank-1 in epilogue)
#pragma unroll
    for (int kk = 0; kk < C_; kk += 32) {
        s16x8 af[4], bfr[8];
#pragma unroll
        for (int mt = 0; mt < 4; ++mt) {
            int w = m0 + mt * 16 + l15;
            if (zb) {
                af[mt] = *(const s16x8*)(zb + w * C_ + kk + q * 8);
            } else {
                const float* ap = zrow + w * C_ + kk + q * 8;
                f32x4 f0 = *(const f32x4*)ap;
                f32x4 f1 = *(const f32x4*)(ap + 4);
                s16x8 t;
#pragma unroll
                for (int j = 0; j < 4; ++j) t[j] = (short)f2bf(f0[j]);
#pragma unroll
                for (int j = 0; j < 4; ++j) t[4 + j] = (short)f2bf(f1[j]);
                af[mt] = t;
            }
        }
#pragma unroll
        for (int nt = 0; nt < 8; ++nt)
            bfr[nt] = *(const s16x8*)(w2t + (nt * 16 + l15) * C_ + kk + q * 8);
#pragma unroll
        for (int mt = 0; mt < 4; ++mt)
#pragma unroll
            for (int nt = 0; nt < 8; ++nt)
                acc[mt][nt] = __builtin_amdgcn_mfma_f32_16x16x32_bf16(af[mt], bfr[nt], acc[mt][nt], 0, 0, 0);
    }
    // ---- epilogue 1: p[w+1] = x[w+1] + sc[w+1] + v[w]  -> LDS bf16
#pragma unroll
    for (int nt = 0; nt < 8; ++nt) {
        int c = nt * 16 + l15;
#pragma unroll
        for (int mt = 0; mt < 4; ++mt) {
#pragma unroll
            for (int r = 0; r < 4; ++r) {
                int w = m0 + mt * 16 + q * 4 + r;
                float v = relu(acc[mt][nt][r] + sc[w] * cs2v[nt] + b2v[nt]);
                if (w < W_ - 1) {
                    float zv = zb ? bf2f(zb[(w + 1) * C_ + c]) : zrow[(w + 1) * C_ + c];
                    float p = zv + sc[w + 1] + v;
                    p_lds[(w + 1) * PS + c] = f2bf(p);
                    if (w == W_ - 2) qrow[(W_ - 1) * C_ + c] = p;   // q[W-1] = p[W-1], exact fp32
                }
            }
        }
    }
    __syncthreads();

    // ---- GEMM2: A = p (bf16, LDS)
#pragma unroll
    for (int mt = 0; mt < 4; ++mt)
#pragma unroll
        for (int nt = 0; nt < 8; ++nt) acc[mt][nt] = (f32x4){0.f, 0.f, 0.f, 0.f};
#pragma unroll
    for (int kk = 0; kk < C_; kk += 32) {
        s16x8 af[4], bfr[8];
#pragma unroll
        for (int mt = 0; mt < 4; ++mt) {
            int w = m0 + mt * 16 + l15;
            af[mt] = *(const s16x8*)(&p_lds[w * PS + kk + q * 8]);
        }
#pragma unroll
        for (int nt = 0; nt < 8; ++nt)
            bfr[nt] = *(const s16x8*)(w2t + (nt * 16 + l15) * C_ + kk + q * 8);
#pragma unroll
        for (int mt = 0; mt < 4; ++mt)
#pragma unroll
            for (int nt = 0; nt < 8; ++nt)
                acc[mt][nt] = __builtin_amdgcn_mfma_f32_16x16x32_bf16(af[mt], bfr[nt], acc[mt][nt], 0, 0, 0);
    }
    // ---- epilogue 2: q stores
#pragma unroll
    for (int nt = 0; nt < 8; ++nt) {
        int c = nt * 16 + l15;
#pragma unroll
        for (int mt = 0; mt < 4; ++mt) {
#pragma unroll
            for (int r = 0; r < 4; ++r) {
                int w = m0 + mt * 16 + q * 4 + r;
                if (w == W_ - 2) continue;       // r[W-2] unused; q[W-1] already stored
                float rr = relu(acc[mt][nt][r] + b2v[nt]);
                float pv = bf2f(p_lds[((w - 1) & (W_ - 1)) * PS + c]);
                int wd = (w <= W_ - 3) ? w : (W_ - 2);   // w==W-1 -> q[W-2] = r[W-1] + p[W-2]
                qrow[wd * C_ + c] = rr + pv;
            }
        }
    }
}

extern "C" void kernel_launch(void* const* d_in, const int* in_sizes, int n_in,
                              void* d_out, int out_size, void* d_ws, size_t ws_size,
                              hipStream_t stream) {
    const float* x  = (const float*)d_in[0];
    const float* w1 = (const float*)d_in[1];
    const float* b1 = (const float*)d_in[2];
    const float* w2 = (const float*)d_in[3];
    const float* b2 = (const float*)d_in[4];
    float* out = (float*)d_out;

    float* wsf = (float*)d_ws;
    // ws layout (floats): c1x[262144] | s1[16] | w2t[8192] | cs2[128] | xb[4194304]
    float* c1x = wsf;
    float* s1  = wsf + 262144;
    unsigned short* w2t = (unsigned short*)(wsf + 262160);
    float* cs2 = wsf + 270352;
    size_t need_bytes = ((size_t)270480 + 4194304) * 4;
    unsigned short* xb = (ws_size >= need_bytes) ? (unsigned short*)(wsf + 270480)
                                                 : (unsigned short*)0;

    k0_conv1<<<B_ * H_ + (C_ * D_) / 256, 256, 0, stream>>>(x, w1, b1, w2, c1x, s1, w2t, cs2, xb);
    k12_fused<<<B_ * H_, 256, 0, stream>>>(x, xb, b2, c1x, s1, w2t, cs2, out);
}